// Round 4
// baseline (2991.921 us; speedup 1.0000x reference)
//
#include <hip/hip_runtime.h>
#include <hip/hip_fp16.h>

#define T_TOK 16384
#define C_DIM 1024
#define F_DIM 4096
#define E_NUM 8

typedef _Float16 half8 __attribute__((ext_vector_type(8)));
typedef float f32x4 __attribute__((ext_vector_type(4)));

// ---- workspace layout (bytes) ----
static constexpr size_t META_OFF  = 0;
static constexpr size_t XB_OFF    = 256;                                      // x fp16 [T][C]
static constexpr size_t W1T_OFF   = XB_OFF  + (size_t)2*T_TOK*C_DIM;          // w1^T fp16 [E][F][C]
static constexpr size_t W2T_OFF   = W1T_OFF + (size_t)2*E_NUM*C_DIM*F_DIM;    // w2^T fp16 [E][C][F]
static constexpr size_t HB_OFF    = W2T_OFF + (size_t)2*E_NUM*C_DIM*F_DIM;    // h fp16 [T*K][F]
static constexpr size_t YB_OFF    = HB_OFF  + (size_t)2*T_TOK*2*F_DIM;        // y fp16 [T*K][C]
static constexpr size_t TOK_OFF   = YB_OFF  + (size_t)2*T_TOK*2*C_DIM;        // int [E][T]
static constexpr size_t GATE_OFF  = TOK_OFF + (size_t)4*E_NUM*T_TOK;          // float [E][T]
static constexpr size_t TSLOT_OFF = GATE_OFF+ (size_t)4*E_NUM*T_TOK;          // int [T][2]
static constexpr size_t WS_NEED   = TSLOT_OFF + (size_t)4*T_TOK*2;

__device__ __forceinline__ void async16(void* lds, const void* g) {
  __builtin_amdgcn_global_load_lds((const __attribute__((address_space(1))) unsigned int*)g,
                                   (__attribute__((address_space(3))) unsigned int*)lds,
                                   16, 0, 0);
}

// ---- cast x fp32 -> fp16 ----
__global__ __launch_bounds__(256) void cast_x_kernel(const float* __restrict__ x,
                                                     _Float16* __restrict__ xb) {
  size_t i = ((size_t)blockIdx.x * 256 + threadIdx.x) * 8;
  float4 a = *(const float4*)(x + i);
  float4 b = *(const float4*)(x + i + 4);
  half8 h;
  h[0]=(_Float16)a.x; h[1]=(_Float16)a.y; h[2]=(_Float16)a.z; h[3]=(_Float16)a.w;
  h[4]=(_Float16)b.x; h[5]=(_Float16)b.y; h[6]=(_Float16)b.z; h[7]=(_Float16)b.w;
  *(half8*)(xb + i) = h;
}

// ---- transpose + cast: in fp32 [R][Cc] per expert -> out fp16 [Cc][R] ----
__global__ __launch_bounds__(256) void transpose_cast_kernel(const float* __restrict__ in,
                                                             _Float16* __restrict__ outp,
                                                             int R, int Cc) {
  __shared__ float tile[32][33];
  int e = blockIdx.z;
  const float* ip = in + (size_t)e * R * Cc;
  _Float16* op = outp + (size_t)e * R * Cc;
  int c0 = blockIdx.x * 32, r0 = blockIdx.y * 32;
  int tx = threadIdx.x & 31, ty = threadIdx.x >> 5;
  #pragma unroll
  for (int d = 0; d < 32; d += 8)
    tile[ty + d][tx] = ip[(size_t)(r0 + ty + d) * Cc + c0 + tx];
  __syncthreads();
  #pragma unroll
  for (int d = 0; d < 32; d += 8)
    op[(size_t)(c0 + ty + d) * R + r0 + tx] = (_Float16)tile[tx][ty + d];
}

// ---- router: fp64 logits, softmax, top-2 (tie -> lower index), gates ----
__global__ __launch_bounds__(256) void router_kernel(const float* __restrict__ x,
                                                     const float* __restrict__ rw,
                                                     int* __restrict__ counts,
                                                     int* __restrict__ tok,
                                                     float* __restrict__ gate,
                                                     int* __restrict__ tslot) {
  int wv = threadIdx.x >> 6, l = threadIdx.x & 63;
  int t = blockIdx.x * 4 + wv;
  const float* xr = x + (size_t)t * C_DIM;
  double acc[E_NUM] = {};
  #pragma unroll
  for (int j = 0; j < 4; ++j) {
    float4 xv = *(const float4*)(xr + j * 256 + l * 4);
    #pragma unroll
    for (int e = 0; e < E_NUM; ++e) {
      float4 w4 = *(const float4*)(rw + (size_t)e * C_DIM + j * 256 + l * 4);
      acc[e] += (double)xv.x * w4.x + (double)xv.y * w4.y +
                (double)xv.z * w4.z + (double)xv.w * w4.w;
    }
  }
  #pragma unroll
  for (int e = 0; e < E_NUM; ++e)
    #pragma unroll
    for (int off = 32; off; off >>= 1)
      acc[e] += __shfl_xor(acc[e], off, 64);

  if (l == 0) {
    double m = acc[0];
    #pragma unroll
    for (int e = 1; e < E_NUM; ++e) m = acc[e] > m ? acc[e] : m;
    double p[E_NUM], s = 0.0;
    #pragma unroll
    for (int e = 0; e < E_NUM; ++e) { p[e] = exp(acc[e] - m); s += p[e]; }
    int i0 = 0; double b0 = p[0];
    #pragma unroll
    for (int e = 1; e < E_NUM; ++e) if (p[e] > b0) { b0 = p[e]; i0 = e; }
    int i1 = -1; double b1v = -1.0;
    #pragma unroll
    for (int e = 0; e < E_NUM; ++e) if (e != i0 && p[e] > b1v) { b1v = p[e]; i1 = e; }
    double q0 = b0 / s, q1 = b1v / s;
    double den = q0 + q1 + 1e-9;
    float g0 = (float)(q0 / den), g1 = (float)(q1 / den);
    int idx0 = atomicAdd(&counts[i0], 1);
    tok[i0 * T_TOK + idx0] = t; gate[i0 * T_TOK + idx0] = g0;
    tslot[t * 2] = (i0 << 24) | idx0;
    int idx1 = atomicAdd(&counts[i1], 1);
    tok[i1 * T_TOK + idx1] = t; gate[i1 * T_TOK + idx1] = g1;
    tslot[t * 2 + 1] = (i1 << 24) | idx1;
  }
}

// ---- prefix sums: rowOff (meta[8..16]) and 128-row tileOff (meta[17..25]) ----
__global__ void plan_kernel(int* meta) {
  if (threadIdx.x == 0 && blockIdx.x == 0) {
    int ro = 0, to = 0;
    meta[8] = 0; meta[17] = 0;
    for (int e = 0; e < E_NUM; ++e) {
      int c = meta[e];
      ro += c; to += (c + 127) >> 7;
      meta[9 + e] = ro; meta[18 + e] = to;
    }
  }
}

// ============================================================================
// m97-family grouped GEMMs: small tiles, single-buffer LDS, 2 barriers per
// K-step, compiler-managed waits; latency hidden by 3-5 co-resident blocks/CU
// (m114 wave-level overlap). Zero-conflict involution swizzle kept:
// LDS slot (row, s) holds source chunk s ^ ((row>>1)&3); reader uses the
// same XOR. LDS row stride = 64 B (4 chunks of 16 B per ks-half).
// ============================================================================

// ---- grouped GEMM1: h = gelu(x[tok] @ w1[e] + b1[e]) ----
// 128x256 tile, BK=64, 8 waves (2M x 4N), LDS 48 KiB -> 3 blocks/CU.
__global__ __launch_bounds__(512, 6) void gemm1_kernel(const _Float16* __restrict__ xb,
                                                       const _Float16* __restrict__ w1t,
                                                       const float* __restrict__ b1,
                                                       _Float16* __restrict__ hbuf,
                                                       const int* __restrict__ tok,
                                                       const int* __restrict__ meta) {
  __shared__ _Float16 smem[24576];   // A 16 KB (2ks x 128r x 64B) + B 32 KB (2ks x 256r x 64B)
  __shared__ int tokLds[128];

  int bid = blockIdx.x;
  int swz = (bid & 7) * 528 + (bid >> 3);     // bijective XCD swizzle (nwg=4224)
  int mt = swz >> 4, nt = swz & 15;           // 16 N-tiles (F/256)
  if (mt >= meta[17 + E_NUM]) return;
  int e = 0;
  while (mt >= meta[18 + e]) ++e;
  int ne = meta[e];
  int r0 = (mt - meta[17 + e]) << 7;
  int valid = ne - r0; if (valid > 128) valid = 128;

  int tid = threadIdx.x;
  if (tid < 128) {
    int r = tid < valid ? tid : valid - 1;
    tokLds[tid] = tok[e * T_TOK + r0 + r];
  }
  __syncthreads();

  // staging sources: thread -> (row = tid>>2, chunk-slot = tid&3)
  int row = tid >> 2, c4 = tid & 3;
  int ch = c4 ^ ((row >> 1) & 3);             // involution; (row+128)>>1 ≡ row>>1 (mod 4)
  const _Float16* aSrc  = xb + (size_t)tokLds[row] * C_DIM + ch * 8;
  const _Float16* bSrc0 = w1t + ((size_t)e * F_DIM + nt * 256 + row) * C_DIM + ch * 8;
  const _Float16* bSrc1 = bSrc0 + (size_t)128 * C_DIM;

  char* SM = (char*)smem;
  char* dst = SM + (size_t)tid * 16;

  int w = tid >> 6, l = tid & 63;
  int wm = w >> 2, wn = w & 3;
  int rl = l & 15, q = l >> 4;
  int swq = (q ^ ((rl >> 1) & 3)) * 16;
  int aBy = wm * 4096 + rl * 64 + swq;            // + ks*8192  + m*1024
  int bBy = 16384 + wn * 4096 + rl * 64 + swq;    // + ks*16384 + n*1024

  f32x4 acc[4][4] = {};
  constexpr int NT = C_DIM / 64;   // 16
  for (int kt = 0; kt < NT; ++kt) {
    __syncthreads();               // all waves done reading previous tile
    int ko = kt * 64;
    async16(dst,          aSrc  + ko);        // A ks0 (rows 0-127)
    async16(dst + 8192,   aSrc  + ko + 32);   // A ks1
    async16(dst + 16384,  bSrc0 + ko);        // B ks0 rows 0-127
    async16(dst + 24576,  bSrc1 + ko);        // B ks0 rows 128-255
    async16(dst + 32768,  bSrc0 + ko + 32);   // B ks1 rows 0-127
    async16(dst + 40960,  bSrc1 + ko + 32);   // B ks1 rows 128-255
    __syncthreads();               // compiler drains vmcnt before barrier
    #pragma unroll
    for (int ks = 0; ks < 2; ++ks) {
      half8 af[4], bf[4];
      #pragma unroll
      for (int m = 0; m < 4; ++m)
        af[m] = *(const half8*)(SM + ks * 8192 + aBy + m * 1024);
      #pragma unroll
      for (int n = 0; n < 4; ++n)
        bf[n] = *(const half8*)(SM + ks * 16384 + bBy + n * 1024);
      #pragma unroll
      for (int m = 0; m < 4; ++m)
        #pragma unroll
        for (int n = 0; n < 4; ++n)
          acc[m][n] = __builtin_amdgcn_mfma_f32_16x16x32_f16(af[m], bf[n], acc[m][n], 0, 0, 0);
    }
  }

  // epilogue
  int hbase = meta[8 + e] + r0;
  float bv[4];
  #pragma unroll
  for (int n = 0; n < 4; ++n)
    bv[n] = b1[(size_t)e * F_DIM + nt * 256 + wn * 64 + n * 16 + rl];
  #pragma unroll
  for (int m = 0; m < 4; ++m) {
    int rb = wm * 64 + m * 16 + q * 4;
    #pragma unroll
    for (int n = 0; n < 4; ++n) {
      int col = nt * 256 + wn * 64 + n * 16 + rl;
      #pragma unroll
      for (int r = 0; r < 4; ++r) {
        int rr = rb + r;
        if (rr < valid) {
          float pre = acc[m][n][r] + bv[n];
          float g = 0.5f * pre * (1.0f + erff(pre * 0.70710678118654752f));
          hbuf[(size_t)(hbase + rr) * F_DIM + col] = (_Float16)g;
        }
      }
    }
  }
}

// ---- grouped GEMM2: ybuf = gate * (h @ w2[e] + b2[e]) ----
// 128x128 tile, BK=64, 4 waves (2M x 2N), LDS 32 KiB -> 5 blocks/CU.
__global__ __launch_bounds__(256, 5) void gemm2_kernel(const _Float16* __restrict__ hbuf,
                                                       const _Float16* __restrict__ w2t,
                                                       const float* __restrict__ b2,
                                                       _Float16* __restrict__ ybuf,
                                                       const float* __restrict__ gate,
                                                       const int* __restrict__ meta) {
  __shared__ _Float16 smem[16384];   // A 16 KB + B 16 KB
  __shared__ float gateLds[128];

  int bid = blockIdx.x;
  int swz = (bid & 7) * 264 + (bid >> 3);     // bijective XCD swizzle (nwg=2112)
  int mt = swz >> 3, nt = swz & 7;            // 8 N-tiles (C/128)
  if (mt >= meta[17 + E_NUM]) return;
  int e = 0;
  while (mt >= meta[18 + e]) ++e;
  int ne = meta[e];
  int r0 = (mt - meta[17 + e]) << 7;
  int valid = ne - r0; if (valid > 128) valid = 128;
  int hbase = meta[8 + e] + r0;

  int tid = threadIdx.x;
  if (tid < 128) {
    int r = tid < valid ? tid : valid - 1;
    gateLds[tid] = gate[e * T_TOK + r0 + r];
  }
  __syncthreads();

  int row = tid >> 2, c4 = tid & 3;           // row 0..63
  int ch = c4 ^ ((row >> 1) & 3);             // (row+64)>>1 ≡ row>>1 (mod 4)
  int rcA0 = row      < valid ? row      : valid - 1;
  int rcA1 = row + 64 < valid ? row + 64 : valid - 1;
  const _Float16* aSrc0 = hbuf + (size_t)(hbase + rcA0) * F_DIM + ch * 8;
  const _Float16* aSrc1 = hbuf + (size_t)(hbase + rcA1) * F_DIM + ch * 8;
  const _Float16* bSrc0 = w2t + ((size_t)e * C_DIM + nt * 128 + row) * F_DIM + ch * 8;
  const _Float16* bSrc1 = bSrc0 + (size_t)64 * F_DIM;

  char* SM = (char*)smem;
  char* dst = SM + (size_t)tid * 16;

  int w = tid >> 6, l = tid & 63;
  int wm = w >> 1, wn = w & 1;
  int rl = l & 15, q = l >> 4;
  int swq = (q ^ ((rl >> 1) & 3)) * 16;
  int aBy = wm * 4096 + rl * 64 + swq;            // + ks*8192 + m*1024
  int bBy = 16384 + wn * 4096 + rl * 64 + swq;    // + ks*8192 + n*1024

  f32x4 acc[4][4] = {};
  constexpr int NT = F_DIM / 64;   // 64
  for (int kt = 0; kt < NT; ++kt) {
    __syncthreads();
    int ko = kt * 64;
    async16(dst,          aSrc0 + ko);         // A ks0 rows 0-63
    async16(dst + 4096,   aSrc1 + ko);         // A ks0 rows 64-127
    async16(dst + 8192,   aSrc0 + ko + 32);    // A ks1 rows 0-63
    async16(dst + 12288,  aSrc1 + ko + 32);    // A ks1 rows 64-127
    async16(dst + 16384,  bSrc0 + ko);         // B ks0 rows 0-63
    async16(dst + 20480,  bSrc1 + ko);         // B ks0 rows 64-127
    async16(dst + 24576,  bSrc0 + ko + 32);    // B ks1 rows 0-63
    async16(dst + 28672,  bSrc1 + ko + 32);    // B ks1 rows 64-127
    __syncthreads();
    #pragma unroll
    for (int ks = 0; ks < 2; ++ks) {
      half8 af[4], bf[4];
      #pragma unroll
      for (int m = 0; m < 4; ++m)
        af[m] = *(const half8*)(SM + ks * 8192 + aBy + m * 1024);
      #pragma unroll
      for (int n = 0; n < 4; ++n)
        bf[n] = *(const half8*)(SM + ks * 8192 + bBy + n * 1024);
      #pragma unroll
      for (int m = 0; m < 4; ++m)
        #pragma unroll
        for (int n = 0; n < 4; ++n)
          acc[m][n] = __builtin_amdgcn_mfma_f32_16x16x32_f16(af[m], bf[n], acc[m][n], 0, 0, 0);
    }
  }

  float bv[4];
  #pragma unroll
  for (int n = 0; n < 4; ++n)
    bv[n] = b2[(size_t)e * C_DIM + nt * 128 + wn * 64 + n * 16 + rl];
  #pragma unroll
  for (int m = 0; m < 4; ++m) {
    int rb = wm * 64 + m * 16 + q * 4;
    #pragma unroll
    for (int n = 0; n < 4; ++n) {
      int col = nt * 128 + wn * 64 + n * 16 + rl;
      #pragma unroll
      for (int r = 0; r < 4; ++r) {
        int rr = rb + r;
        if (rr < valid) {
          float val = gateLds[rr] * (acc[m][n][r] + bv[n]);
          ybuf[(size_t)(hbase + rr) * C_DIM + col] = (_Float16)val;
        }
      }
    }
  }
}

// ---- combine: out[t] = y(slot0) + y(slot1) ----
__global__ __launch_bounds__(256) void combine_kernel(const _Float16* __restrict__ ybuf,
                                                      const int* __restrict__ tslot,
                                                      const int* __restrict__ meta,
                                                      float* __restrict__ out) {
  int gid = blockIdx.x * 256 + threadIdx.x;
  int t = gid >> 7;
  int cc = (gid & 127) << 3;
  int s0 = tslot[t * 2], s1 = tslot[t * 2 + 1];
  size_t r0 = (size_t)meta[8 + (s0 >> 24)] + (s0 & 0xFFFFFF);
  size_t r1 = (size_t)meta[8 + (s1 >> 24)] + (s1 & 0xFFFFFF);
  half8 y0 = *(const half8*)(ybuf + r0 * C_DIM + cc);
  half8 y1 = *(const half8*)(ybuf + r1 * C_DIM + cc);
  float4 o0, o1;
  o0.x = (float)y0[0] + (float)y1[0];
  o0.y = (float)y0[1] + (float)y1[1];
  o0.z = (float)y0[2] + (float)y1[2];
  o0.w = (float)y0[3] + (float)y1[3];
  o1.x = (float)y0[4] + (float)y1[4];
  o1.y = (float)y0[5] + (float)y1[5];
  o1.z = (float)y0[6] + (float)y1[6];
  o1.w = (float)y0[7] + (float)y1[7];
  *(float4*)(out + (size_t)t * C_DIM + cc) = o0;
  *(float4*)(out + (size_t)t * C_DIM + cc + 4) = o1;
}

extern "C" void kernel_launch(void* const* d_in, const int* in_sizes, int n_in,
                              void* d_out, int out_size, void* d_ws, size_t ws_size,
                              hipStream_t stream) {
  (void)in_sizes; (void)n_in; (void)out_size;
  if (!d_ws || ws_size < WS_NEED) return;  // need ~481 MiB scratch

  const float* x  = (const float*)d_in[0];
  const float* rw = (const float*)d_in[1];
  const float* w1 = (const float*)d_in[2];
  const float* b1 = (const float*)d_in[3];
  const float* w2 = (const float*)d_in[4];
  const float* b2 = (const float*)d_in[5];
  float* out = (float*)d_out;

  char* ws = (char*)d_ws;
  int*       meta  = (int*)(ws + META_OFF);
  _Float16*  xb    = (_Float16*)(ws + XB_OFF);
  _Float16*  w1t   = (_Float16*)(ws + W1T_OFF);
  _Float16*  w2t   = (_Float16*)(ws + W2T_OFF);
  _Float16*  hbuf  = (_Float16*)(ws + HB_OFF);
  _Float16*  ybuf  = (_Float16*)(ws + YB_OFF);
  int*       tok   = (int*)(ws + TOK_OFF);
  float*     gate  = (float*)(ws + GATE_OFF);
  int*       tslot = (int*)(ws + TSLOT_OFF);

  hipMemsetAsync(meta, 0, 256, stream);

  cast_x_kernel<<<(T_TOK * C_DIM / 8) / 256, 256, 0, stream>>>(x, xb);
  transpose_cast_kernel<<<dim3(F_DIM / 32, C_DIM / 32, E_NUM), 256, 0, stream>>>(w1, w1t, C_DIM, F_DIM);
  transpose_cast_kernel<<<dim3(C_DIM / 32, F_DIM / 32, E_NUM), 256, 0, stream>>>(w2, w2t, F_DIM, C_DIM);
  router_kernel<<<T_TOK / 4, 256, 0, stream>>>(x, rw, meta, tok, gate, tslot);
  plan_kernel<<<1, 64, 0, stream>>>(meta);

  // max 128-row M-tiles = T*K/128 + (E-1) = 263 -> launch 264 (x%8==0 for XCD swizzle)
  gemm1_kernel<<<264 * 16, 512, 0, stream>>>(xb, w1t, b1, hbuf, tok, meta);
  gemm2_kernel<<<264 * 8, 256, 0, stream>>>(hbuf, w2t, b2, ybuf, gate, meta);
  combine_kernel<<<(T_TOK * (C_DIM / 8)) / 256, 256, 0, stream>>>(ybuf, tslot, meta, out);
}

// Round 5
// 1347.315 us; speedup vs baseline: 2.2207x; 2.2207x over previous
//
#include <hip/hip_runtime.h>
#include <hip/hip_fp16.h>

#define T_TOK 16384
#define C_DIM 1024
#define F_DIM 4096
#define E_NUM 8

typedef _Float16 half8 __attribute__((ext_vector_type(8)));
typedef float f32x4 __attribute__((ext_vector_type(4)));

// ---- workspace layout (bytes) ----
static constexpr size_t META_OFF  = 0;
static constexpr size_t XB_OFF    = 256;                                      // x fp16 [T][C]
static constexpr size_t W1T_OFF   = XB_OFF  + (size_t)2*T_TOK*C_DIM;          // w1^T fp16 [E][F][C]
static constexpr size_t W2T_OFF   = W1T_OFF + (size_t)2*E_NUM*C_DIM*F_DIM;    // w2^T fp16 [E][C][F]
static constexpr size_t HB_OFF    = W2T_OFF + (size_t)2*E_NUM*C_DIM*F_DIM;    // h fp16 [T*K][F]
static constexpr size_t YB_OFF    = HB_OFF  + (size_t)2*T_TOK*2*F_DIM;        // y fp16 [T*K][C]
static constexpr size_t TOK_OFF   = YB_OFF  + (size_t)2*T_TOK*2*C_DIM;        // int [E][T]
static constexpr size_t GATE_OFF  = TOK_OFF + (size_t)4*E_NUM*T_TOK;          // float [E][T]
static constexpr size_t TSLOT_OFF = GATE_OFF+ (size_t)4*E_NUM*T_TOK;          // int [T][2]
static constexpr size_t WS_NEED   = TSLOT_OFF + (size_t)4*T_TOK*2;

__device__ __forceinline__ void async16(void* lds, const void* g) {
  __builtin_amdgcn_global_load_lds((const __attribute__((address_space(1))) unsigned int*)g,
                                   (__attribute__((address_space(3))) unsigned int*)lds,
                                   16, 0, 0);
}

// ---- cast x fp32 -> fp16 ----
__global__ __launch_bounds__(256) void cast_x_kernel(const float* __restrict__ x,
                                                     _Float16* __restrict__ xb) {
  size_t i = ((size_t)blockIdx.x * 256 + threadIdx.x) * 8;
  float4 a = *(const float4*)(x + i);
  float4 b = *(const float4*)(x + i + 4);
  half8 h;
  h[0]=(_Float16)a.x; h[1]=(_Float16)a.y; h[2]=(_Float16)a.z; h[3]=(_Float16)a.w;
  h[4]=(_Float16)b.x; h[5]=(_Float16)b.y; h[6]=(_Float16)b.z; h[7]=(_Float16)b.w;
  *(half8*)(xb + i) = h;
}

// ---- transpose + cast: in fp32 [R][Cc] per expert -> out fp16 [Cc][R] ----
__global__ __launch_bounds__(256) void transpose_cast_kernel(const float* __restrict__ in,
                                                             _Float16* __restrict__ outp,
                                                             int R, int Cc) {
  __shared__ float tile[32][33];
  int e = blockIdx.z;
  const float* ip = in + (size_t)e * R * Cc;
  _Float16* op = outp + (size_t)e * R * Cc;
  int c0 = blockIdx.x * 32, r0 = blockIdx.y * 32;
  int tx = threadIdx.x & 31, ty = threadIdx.x >> 5;
  #pragma unroll
  for (int d = 0; d < 32; d += 8)
    tile[ty + d][tx] = ip[(size_t)(r0 + ty + d) * Cc + c0 + tx];
  __syncthreads();
  #pragma unroll
  for (int d = 0; d < 32; d += 8)
    op[(size_t)(c0 + ty + d) * R + r0 + tx] = (_Float16)tile[tx][ty + d];
}

// ---- router: fp64 logits, softmax, top-2 (tie -> lower index), gates ----
__global__ __launch_bounds__(256) void router_kernel(const float* __restrict__ x,
                                                     const float* __restrict__ rw,
                                                     int* __restrict__ counts,
                                                     int* __restrict__ tok,
                                                     float* __restrict__ gate,
                                                     int* __restrict__ tslot) {
  int wv = threadIdx.x >> 6, l = threadIdx.x & 63;
  int t = blockIdx.x * 4 + wv;
  const float* xr = x + (size_t)t * C_DIM;
  double acc[E_NUM] = {};
  #pragma unroll
  for (int j = 0; j < 4; ++j) {
    float4 xv = *(const float4*)(xr + j * 256 + l * 4);
    #pragma unroll
    for (int e = 0; e < E_NUM; ++e) {
      float4 w4 = *(const float4*)(rw + (size_t)e * C_DIM + j * 256 + l * 4);
      acc[e] += (double)xv.x * w4.x + (double)xv.y * w4.y +
                (double)xv.z * w4.z + (double)xv.w * w4.w;
    }
  }
  #pragma unroll
  for (int e = 0; e < E_NUM; ++e)
    #pragma unroll
    for (int off = 32; off; off >>= 1)
      acc[e] += __shfl_xor(acc[e], off, 64);

  if (l == 0) {
    double m = acc[0];
    #pragma unroll
    for (int e = 1; e < E_NUM; ++e) m = acc[e] > m ? acc[e] : m;
    double p[E_NUM], s = 0.0;
    #pragma unroll
    for (int e = 0; e < E_NUM; ++e) { p[e] = exp(acc[e] - m); s += p[e]; }
    int i0 = 0; double b0 = p[0];
    #pragma unroll
    for (int e = 1; e < E_NUM; ++e) if (p[e] > b0) { b0 = p[e]; i0 = e; }
    int i1 = -1; double b1v = -1.0;
    #pragma unroll
    for (int e = 0; e < E_NUM; ++e) if (e != i0 && p[e] > b1v) { b1v = p[e]; i1 = e; }
    double q0 = b0 / s, q1 = b1v / s;
    double den = q0 + q1 + 1e-9;
    float g0 = (float)(q0 / den), g1 = (float)(q1 / den);
    int idx0 = atomicAdd(&counts[i0], 1);
    tok[i0 * T_TOK + idx0] = t; gate[i0 * T_TOK + idx0] = g0;
    tslot[t * 2] = (i0 << 24) | idx0;
    int idx1 = atomicAdd(&counts[i1], 1);
    tok[i1 * T_TOK + idx1] = t; gate[i1 * T_TOK + idx1] = g1;
    tslot[t * 2 + 1] = (i1 << 24) | idx1;
  }
}

// ---- prefix sums: rowOff (meta[8..16]) and 128-row tileOff (meta[17..25]) ----
__global__ void plan_kernel(int* meta) {
  if (threadIdx.x == 0 && blockIdx.x == 0) {
    int ro = 0, to = 0;
    meta[8] = 0; meta[17] = 0;
    for (int e = 0; e < E_NUM; ++e) {
      int c = meta[e];
      ro += c; to += (c + 127) >> 7;
      meta[9 + e] = ro; meta[18 + e] = to;
    }
  }
}

// ============================================================================
// m97-family grouped GEMMs: single-buffer LDS, 2 barriers per K-step,
// compiler-managed waits; latency hidden by 2-4 co-resident blocks/CU.
// NO __launch_bounds__ occupancy arg: R4 proved a waves/EU declaration of
// 5-6 caps VGPR at ~85-102 < the ~120 this kernel needs -> acc spill ->
// 6 GB scratch traffic. Natural allocation (~104-120 VGPR, <=128) gives
// 16 waves/CU, LDS is then the binding limit.
// Zero-conflict involution swizzle (R2-proven): LDS slot (row, s) holds
// source chunk s ^ ((row>>1)&3); reader XORs the same. Row stride 64 B.
// Block ordering: XCD chunk -> 8-mt bands x all nt (A-band ~2 MB in L2).
// ============================================================================

// ---- grouped GEMM1: h = gelu(x[tok] @ w1[e] + b1[e]) ----
// 128x256 tile, BK=64, 8 waves (2M x 4N), LDS 48.5 KiB.
__global__ __launch_bounds__(512) void gemm1_kernel(const _Float16* __restrict__ xb,
                                                    const _Float16* __restrict__ w1t,
                                                    const float* __restrict__ b1,
                                                    _Float16* __restrict__ hbuf,
                                                    const int* __restrict__ tok,
                                                    const int* __restrict__ meta) {
  __shared__ _Float16 smem[24576];   // A 16 KB (2ks x 128r x 64B) + B 32 KB (2ks x 256r x 64B)
  __shared__ int tokLds[128];

  // XCD swizzle (nwg=4224, chunk 528) + 8mt x 16nt banding for L2 reuse
  int bid = blockIdx.x;
  int swz = (bid & 7) * 528 + (bid >> 3);
  int band = swz >> 7, rem = swz & 127;
  int nt = rem >> 3;
  int mt = band * 8 + (rem & 7);
  if (mt >= meta[17 + E_NUM]) return;
  int e = 0;
  while (mt >= meta[18 + e]) ++e;
  int ne = meta[e];
  int r0 = (mt - meta[17 + e]) << 7;
  int valid = ne - r0; if (valid > 128) valid = 128;

  int tid = threadIdx.x;
  if (tid < 128) {
    int r = tid < valid ? tid : valid - 1;
    tokLds[tid] = tok[e * T_TOK + r0 + r];
  }
  __syncthreads();

  // staging sources: thread -> (row = tid>>2, chunk-slot = tid&3)
  int row = tid >> 2, c4 = tid & 3;
  int ch = c4 ^ ((row >> 1) & 3);             // involution; (row+128)>>1 ≡ row>>1 (mod 4)
  const _Float16* aSrc  = xb + (size_t)tokLds[row] * C_DIM + ch * 8;
  const _Float16* bSrc0 = w1t + ((size_t)e * F_DIM + nt * 256 + row) * C_DIM + ch * 8;
  const _Float16* bSrc1 = bSrc0 + (size_t)128 * C_DIM;

  char* SM = (char*)smem;
  char* dst = SM + (size_t)tid * 16;

  int w = tid >> 6, l = tid & 63;
  int wm = w >> 2, wn = w & 3;
  int rl = l & 15, q = l >> 4;
  int swq = (q ^ ((rl >> 1) & 3)) * 16;
  int aBy = wm * 4096 + rl * 64 + swq;            // + ks*8192  + m*1024
  int bBy = 16384 + wn * 4096 + rl * 64 + swq;    // + ks*16384 + n*1024

  f32x4 acc[4][4] = {};
  constexpr int NT = C_DIM / 64;   // 16
  for (int kt = 0; kt < NT; ++kt) {
    __syncthreads();               // all waves done reading previous tile
    int ko = kt * 64;
    async16(dst,          aSrc  + ko);        // A ks0 (rows 0-127)
    async16(dst + 8192,   aSrc  + ko + 32);   // A ks1
    async16(dst + 16384,  bSrc0 + ko);        // B ks0 rows 0-127
    async16(dst + 24576,  bSrc1 + ko);        // B ks0 rows 128-255
    async16(dst + 32768,  bSrc0 + ko + 32);   // B ks1 rows 0-127
    async16(dst + 40960,  bSrc1 + ko + 32);   // B ks1 rows 128-255
    __syncthreads();               // compiler drains vmcnt before barrier
    #pragma unroll
    for (int ks = 0; ks < 2; ++ks) {
      half8 af[4], bf[4];
      #pragma unroll
      for (int m = 0; m < 4; ++m)
        af[m] = *(const half8*)(SM + ks * 8192 + aBy + m * 1024);
      #pragma unroll
      for (int n = 0; n < 4; ++n)
        bf[n] = *(const half8*)(SM + ks * 16384 + bBy + n * 1024);
      #pragma unroll
      for (int m = 0; m < 4; ++m)
        #pragma unroll
        for (int n = 0; n < 4; ++n)
          acc[m][n] = __builtin_amdgcn_mfma_f32_16x16x32_f16(af[m], bf[n], acc[m][n], 0, 0, 0);
    }
  }

  // epilogue
  int hbase = meta[8 + e] + r0;
  float bv[4];
  #pragma unroll
  for (int n = 0; n < 4; ++n)
    bv[n] = b1[(size_t)e * F_DIM + nt * 256 + wn * 64 + n * 16 + rl];
  #pragma unroll
  for (int m = 0; m < 4; ++m) {
    int rb = wm * 64 + m * 16 + q * 4;
    #pragma unroll
    for (int n = 0; n < 4; ++n) {
      int col = nt * 256 + wn * 64 + n * 16 + rl;
      #pragma unroll
      for (int r = 0; r < 4; ++r) {
        int rr = rb + r;
        if (rr < valid) {
          float pre = acc[m][n][r] + bv[n];
          float g = 0.5f * pre * (1.0f + erff(pre * 0.70710678118654752f));
          hbuf[(size_t)(hbase + rr) * F_DIM + col] = (_Float16)g;
        }
      }
    }
  }
}

// ---- grouped GEMM2: ybuf = gate * (h @ w2[e] + b2[e]) ----
// 128x128 tile, BK=64, 4 waves (2M x 2N), LDS 32.5 KiB -> 4 blocks/CU.
__global__ __launch_bounds__(256) void gemm2_kernel(const _Float16* __restrict__ hbuf,
                                                    const _Float16* __restrict__ w2t,
                                                    const float* __restrict__ b2,
                                                    _Float16* __restrict__ ybuf,
                                                    const float* __restrict__ gate,
                                                    const int* __restrict__ meta) {
  __shared__ _Float16 smem[16384];   // A 16 KB + B 16 KB
  __shared__ float gateLds[128];

  // XCD swizzle (nwg=2112, chunk 264) + 8mt x 8nt banding
  int bid = blockIdx.x;
  int swz = (bid & 7) * 264 + (bid >> 3);
  int band = swz >> 6, rem = swz & 63;
  int nt = rem >> 3;
  int mt = band * 8 + (rem & 7);
  if (mt >= meta[17 + E_NUM]) return;
  int e = 0;
  while (mt >= meta[18 + e]) ++e;
  int ne = meta[e];
  int r0 = (mt - meta[17 + e]) << 7;
  int valid = ne - r0; if (valid > 128) valid = 128;
  int hbase = meta[8 + e] + r0;

  int tid = threadIdx.x;
  if (tid < 128) {
    int r = tid < valid ? tid : valid - 1;
    gateLds[tid] = gate[e * T_TOK + r0 + r];
  }
  __syncthreads();

  int row = tid >> 2, c4 = tid & 3;           // row 0..63
  int ch = c4 ^ ((row >> 1) & 3);             // (row+64)>>1 ≡ row>>1 (mod 4)
  int rcA0 = row      < valid ? row      : valid - 1;
  int rcA1 = row + 64 < valid ? row + 64 : valid - 1;
  const _Float16* aSrc0 = hbuf + (size_t)(hbase + rcA0) * F_DIM + ch * 8;
  const _Float16* aSrc1 = hbuf + (size_t)(hbase + rcA1) * F_DIM + ch * 8;
  const _Float16* bSrc0 = w2t + ((size_t)e * C_DIM + nt * 128 + row) * F_DIM + ch * 8;
  const _Float16* bSrc1 = bSrc0 + (size_t)64 * F_DIM;

  char* SM = (char*)smem;
  char* dst = SM + (size_t)tid * 16;

  int w = tid >> 6, l = tid & 63;
  int wm = w >> 1, wn = w & 1;
  int rl = l & 15, q = l >> 4;
  int swq = (q ^ ((rl >> 1) & 3)) * 16;
  int aBy = wm * 4096 + rl * 64 + swq;            // + ks*8192 + m*1024
  int bBy = 16384 + wn * 4096 + rl * 64 + swq;    // + ks*8192 + n*1024

  f32x4 acc[4][4] = {};
  constexpr int NT = F_DIM / 64;   // 64
  for (int kt = 0; kt < NT; ++kt) {
    __syncthreads();
    int ko = kt * 64;
    async16(dst,          aSrc0 + ko);         // A ks0 rows 0-63
    async16(dst + 4096,   aSrc1 + ko);         // A ks0 rows 64-127
    async16(dst + 8192,   aSrc0 + ko + 32);    // A ks1 rows 0-63
    async16(dst + 12288,  aSrc1 + ko + 32);    // A ks1 rows 64-127
    async16(dst + 16384,  bSrc0 + ko);         // B ks0 rows 0-63
    async16(dst + 20480,  bSrc1 + ko);         // B ks0 rows 64-127
    async16(dst + 24576,  bSrc0 + ko + 32);    // B ks1 rows 0-63
    async16(dst + 28672,  bSrc1 + ko + 32);    // B ks1 rows 64-127
    __syncthreads();
    #pragma unroll
    for (int ks = 0; ks < 2; ++ks) {
      half8 af[4], bf[4];
      #pragma unroll
      for (int m = 0; m < 4; ++m)
        af[m] = *(const half8*)(SM + ks * 8192 + aBy + m * 1024);
      #pragma unroll
      for (int n = 0; n < 4; ++n)
        bf[n] = *(const half8*)(SM + ks * 8192 + bBy + n * 1024);
      #pragma unroll
      for (int m = 0; m < 4; ++m)
        #pragma unroll
        for (int n = 0; n < 4; ++n)
          acc[m][n] = __builtin_amdgcn_mfma_f32_16x16x32_f16(af[m], bf[n], acc[m][n], 0, 0, 0);
    }
  }

  float bv[4];
  #pragma unroll
  for (int n = 0; n < 4; ++n)
    bv[n] = b2[(size_t)e * C_DIM + nt * 128 + wn * 64 + n * 16 + rl];
  #pragma unroll
  for (int m = 0; m < 4; ++m) {
    int rb = wm * 64 + m * 16 + q * 4;
    #pragma unroll
    for (int n = 0; n < 4; ++n) {
      int col = nt * 128 + wn * 64 + n * 16 + rl;
      #pragma unroll
      for (int r = 0; r < 4; ++r) {
        int rr = rb + r;
        if (rr < valid) {
          float val = gateLds[rr] * (acc[m][n][r] + bv[n]);
          ybuf[(size_t)(hbase + rr) * C_DIM + col] = (_Float16)val;
        }
      }
    }
  }
}

// ---- combine: out[t] = y(slot0) + y(slot1) ----
__global__ __launch_bounds__(256) void combine_kernel(const _Float16* __restrict__ ybuf,
                                                      const int* __restrict__ tslot,
                                                      const int* __restrict__ meta,
                                                      float* __restrict__ out) {
  int gid = blockIdx.x * 256 + threadIdx.x;
  int t = gid >> 7;
  int cc = (gid & 127) << 3;
  int s0 = tslot[t * 2], s1 = tslot[t * 2 + 1];
  size_t r0 = (size_t)meta[8 + (s0 >> 24)] + (s0 & 0xFFFFFF);
  size_t r1 = (size_t)meta[8 + (s1 >> 24)] + (s1 & 0xFFFFFF);
  half8 y0 = *(const half8*)(ybuf + r0 * C_DIM + cc);
  half8 y1 = *(const half8*)(ybuf + r1 * C_DIM + cc);
  float4 o0, o1;
  o0.x = (float)y0[0] + (float)y1[0];
  o0.y = (float)y0[1] + (float)y1[1];
  o0.z = (float)y0[2] + (float)y1[2];
  o0.w = (float)y0[3] + (float)y1[3];
  o1.x = (float)y0[4] + (float)y1[4];
  o1.y = (float)y0[5] + (float)y1[5];
  o1.z = (float)y0[6] + (float)y1[6];
  o1.w = (float)y0[7] + (float)y1[7];
  *(float4*)(out + (size_t)t * C_DIM + cc) = o0;
  *(float4*)(out + (size_t)t * C_DIM + cc + 4) = o1;
}

extern "C" void kernel_launch(void* const* d_in, const int* in_sizes, int n_in,
                              void* d_out, int out_size, void* d_ws, size_t ws_size,
                              hipStream_t stream) {
  (void)in_sizes; (void)n_in; (void)out_size;
  if (!d_ws || ws_size < WS_NEED) return;  // need ~481 MiB scratch

  const float* x  = (const float*)d_in[0];
  const float* rw = (const float*)d_in[1];
  const float* w1 = (const float*)d_in[2];
  const float* b1 = (const float*)d_in[3];
  const float* w2 = (const float*)d_in[4];
  const float* b2 = (const float*)d_in[5];
  float* out = (float*)d_out;

  char* ws = (char*)d_ws;
  int*       meta  = (int*)(ws + META_OFF);
  _Float16*  xb    = (_Float16*)(ws + XB_OFF);
  _Float16*  w1t   = (_Float16*)(ws + W1T_OFF);
  _Float16*  w2t   = (_Float16*)(ws + W2T_OFF);
  _Float16*  hbuf  = (_Float16*)(ws + HB_OFF);
  _Float16*  ybuf  = (_Float16*)(ws + YB_OFF);
  int*       tok   = (int*)(ws + TOK_OFF);
  float*     gate  = (float*)(ws + GATE_OFF);
  int*       tslot = (int*)(ws + TSLOT_OFF);

  hipMemsetAsync(meta, 0, 256, stream);

  cast_x_kernel<<<(T_TOK * C_DIM / 8) / 256, 256, 0, stream>>>(x, xb);
  transpose_cast_kernel<<<dim3(F_DIM / 32, C_DIM / 32, E_NUM), 256, 0, stream>>>(w1, w1t, C_DIM, F_DIM);
  transpose_cast_kernel<<<dim3(C_DIM / 32, F_DIM / 32, E_NUM), 256, 0, stream>>>(w2, w2t, F_DIM, C_DIM);
  router_kernel<<<T_TOK / 4, 256, 0, stream>>>(x, rw, meta, tok, gate, tslot);
  plan_kernel<<<1, 64, 0, stream>>>(meta);

  // max 128-row M-tiles = T*K/128 + (E-1) = 263 -> launch 264 (x%8==0 for XCD swizzle)
  gemm1_kernel<<<264 * 16, 512, 0, stream>>>(xb, w1t, b1, hbuf, tok, meta);
  gemm2_kernel<<<264 * 8, 256, 0, stream>>>(hbuf, w2t, b2, ybuf, gate, meta);
  combine_kernel<<<(T_TOK * (C_DIM / 8)) / 256, 256, 0, stream>>>(ybuf, tslot, meta, out);
}